// Round 4
// baseline (266.950 us; speedup 1.0000x reference)
//
#include <hip/hip_runtime.h>
#include <cstdint>
#include <cstddef>

// ---------- types ----------
typedef __bf16 bf16_t;
typedef __bf16 bf16x8 __attribute__((ext_vector_type(8)));
typedef __bf16 bf16x4 __attribute__((ext_vector_type(4)));
typedef float  f32x4  __attribute__((ext_vector_type(4)));

#define MFMA_BF16(a, b, c) __builtin_amdgcn_mfma_f32_16x16x32_bf16((a), (b), (c), 0, 0, 0)

// async global->LDS, 16B per lane. LDS dest must be wave-uniform base + lane*16.
__device__ __forceinline__ void async_load16(const void* g, void* l) {
    __builtin_amdgcn_global_load_lds((const __attribute__((address_space(1))) void*)g,
                                     (__attribute__((address_space(3))) void*)l,
                                     16, 0, 0);
}

// ---------- problem constants ----------
#define Bq   2
#define Tq   2048
#define Cq   1024
#define Hq   16
#define HSq  64
#define LDQKV 3072   // 3*C
#define Mrows 4096   // B*T

// ---------- fp32 -> bf16 convert ----------
__global__ void cvt_f32_bf16(const float* __restrict__ in, bf16_t* __restrict__ out, int n) {
    int i = (blockIdx.x * blockDim.x + threadIdx.x) * 4;
    if (i + 3 < n) {
        float4 v = *(const float4*)(in + i);
        bf16x4 o;
        o[0] = (bf16_t)v.x; o[1] = (bf16_t)v.y; o[2] = (bf16_t)v.z; o[3] = (bf16_t)v.w;
        *(bf16x4*)(out + i) = o;
    }
}

// ---------- GEMM: C[m][n] = sum_k A[m][k]*B[n][k], A:[M,K], B:[N,K] row-major ----------
// EPI=1: fp32 out + bias.  EPI=2: QKV split epilogue -> Qc [4096][1024],
// Kc [32][2048][64] compact, Vt [32][64][2048] transposed.
template <int BM, int EPI>
__global__ __launch_bounds__(256)
void gemm_bt(const bf16_t* __restrict__ A, const bf16_t* __restrict__ B,
             void* __restrict__ Cout, const float* __restrict__ bias,
             bf16_t* __restrict__ qc, bf16_t* __restrict__ kc, bf16_t* __restrict__ vtp,
             int M, int N, int K) {
    constexpr int MR = BM / 32;   // MFMA row-tiles per wave
    __shared__ __align__(16) bf16_t As[BM * 32];
    __shared__ __align__(16) bf16_t Bs[128 * 32];

    const int tid  = threadIdx.x;
    const int wave = tid >> 6;
    const int lane = tid & 63;
    const int m0 = blockIdx.y * BM;
    const int n0 = blockIdx.x * 128;
    const int wm = (wave >> 1) * (BM / 2);
    const int wn = (wave & 1) * 64;
    const int lrow = lane & 15;
    const int lko  = (lane >> 4) * 8;

    f32x4 acc[MR][4] = {};

    const bf16_t* Ag = A + (size_t)m0 * K;
    const bf16_t* Bg = B + (size_t)n0 * K;
    const int c0 = tid, c1 = tid + 256;

    for (int k0 = 0; k0 < K; k0 += 32) {
        async_load16(Ag + (size_t)(c0 >> 2) * K + k0 + (c0 & 3) * 8, &As[c0 * 8]);
        if (BM == 128)
            async_load16(Ag + (size_t)(c1 >> 2) * K + k0 + (c1 & 3) * 8, &As[c1 * 8]);
        async_load16(Bg + (size_t)(c0 >> 2) * K + k0 + (c0 & 3) * 8, &Bs[c0 * 8]);
        async_load16(Bg + (size_t)(c1 >> 2) * K + k0 + (c1 & 3) * 8, &Bs[c1 * 8]);
        __syncthreads();

        bf16x8 af[MR], bfr[4];
        #pragma unroll
        for (int r = 0; r < MR; r++) af[r] = *(const bf16x8*)&As[(wm + r * 16 + lrow) * 32 + lko];
        #pragma unroll
        for (int c = 0; c < 4; c++) bfr[c] = *(const bf16x8*)&Bs[(wn + c * 16 + lrow) * 32 + lko];
        #pragma unroll
        for (int r = 0; r < MR; r++)
            #pragma unroll
            for (int c = 0; c < 4; c++)
                acc[r][c] = MFMA_BF16(af[r], bfr[c], acc[r][c]);
        __syncthreads();
    }

    const int er = (lane >> 4) * 4;
    const int ec = lane & 15;
    #pragma unroll
    for (int r = 0; r < MR; r++) {
        #pragma unroll
        for (int c = 0; c < 4; c++) {
            int m = m0 + wm + r * 16 + er;
            int n = n0 + wn + c * 16 + ec;
            if (EPI == 1) {
                #pragma unroll
                for (int v = 0; v < 4; v++)
                    ((float*)Cout)[(size_t)(m + v) * N + n] = acc[r][c][v] + bias[n];
            } else {
                int bb = m >> 11, t = m & 2047;   // block-uniform region (n0 128-aligned)
                if (n < 1024) {
                    #pragma unroll
                    for (int v = 0; v < 4; v++)
                        qc[(size_t)(m + v) * 1024 + n] = (bf16_t)acc[r][c][v];
                } else if (n < 2048) {
                    int h = (n - 1024) >> 6, d = (n - 1024) & 63;
                    bf16_t* p = kc + ((size_t)(bb * 16 + h) * Tq + t) * 64 + d;
                    #pragma unroll
                    for (int v = 0; v < 4; v++) p[v * 64] = (bf16_t)acc[r][c][v];
                } else {
                    int h = (n - 2048) >> 6, d = (n - 2048) & 63;
                    bf16x4 o;
                    #pragma unroll
                    for (int v = 0; v < 4; v++) o[v] = (bf16_t)acc[r][c][v];
                    *(bf16x4*)&vtp[((size_t)(bb * 16 + h) * 64 + d) * Tq + t] = o;
                }
            }
        }
    }
}

// ---------- barrier-free attention, Q-tile 128, direct-global K/V fragments ----------
// block = (bh, Q-tile Qi of 128 rows, half). Wave w owns q rows [q0+32w, q0+32w+32).
// S^T = K Q^T (C: rows=keys, cols=q) -> softplus(log2 domain; scale cancels in O/||w||)
// -> per-wave Ws round-trip (C->A layout) -> O += W V. No __syncthreads anywhere.
__global__ __launch_bounds__(256, 4)
void attn_kernel(const bf16_t* __restrict__ Qc, const bf16_t* __restrict__ Kc,
                 const bf16_t* __restrict__ Vt,
                 bf16_t* __restrict__ Opart0, bf16_t* __restrict__ Opart1,
                 float* __restrict__ n2part) {
    __shared__ __align__(16) bf16_t Ws[4][32 * 72];  // per-wave private, stride-72 pad

    const int tid = threadIdx.x;
    const int wave = tid >> 6;
    const int lane = tid & 63;
    const int lrow = lane & 15;
    const int lg   = lane >> 4;
    const int er   = lg * 4;
    const int ec   = lrow;

    const int raw  = blockIdx.x;        // 0..31, heavy-first
    const int Qi   = 15 - (raw >> 1);
    const int half = raw & 1;
    const int bh   = blockIdx.y;
    const int b    = bh >> 4, h = bh & 15;

    const int q0 = Qi * 128;
    const int qw = q0 + wave * 32;          // wave's first q row
    const int nt  = 2 * Qi + 2;
    const int nh2 = Qi + 1;
    const int lo  = half ? nh2 : 0;
    const int hi  = half ? nt : nh2;
    const int hiw = min(hi, (qw + 95) >> 6);  // wave-level causal trim

    const bf16_t* Qb = Qc + (size_t)b * Tq * Cq + h * 64;
    const bf16_t* Kb = Kc + (size_t)bh * Tq * 64;
    const bf16_t* Vb = Vt + (size_t)bh * 64 * Tq;
    bf16_t* wsm = &Ws[wave][0];

    // Q fragments (B-operand for S^T): set t covers q = qw + 16t + lrow
    bf16x8 qf[2][2];
    #pragma unroll
    for (int t = 0; t < 2; t++)
        #pragma unroll
        for (int s = 0; s < 2; s++)
            qf[t][s] = *(const bf16x8*)&Qb[(qw + 16 * t + lrow) * Cq + s * 32 + lg * 8];

    f32x4 oacc[2][4] = {};
    float n2[2] = {0.f, 0.f};
    const float C1 = 0.18033688f;  // 0.125 * log2(e)

    for (int kt = lo; kt < hiw; kt++) {
        const int key0 = kt * 64;

        // K fragments direct from global (compact 8KB tile; L1-shared across waves)
        bf16x8 kf[4][2];
        #pragma unroll
        for (int j = 0; j < 4; j++)
            #pragma unroll
            for (int s = 0; s < 2; s++)
                kf[j][s] = *(const bf16x8*)&Kb[(key0 + 16 * j + lrow) * 64 + s * 32 + lg * 8];

        // ---- set t=0: S^T MFMA then softplus+Ws (keeps sacc live range at 16 VGPR) ----
        #pragma unroll
        for (int t = 0; t < 2; t++) {
            f32x4 sacc[4];
            #pragma unroll
            for (int j = 0; j < 4; j++) {
                f32x4 z = {};
                z = MFMA_BF16(kf[j][0], qf[t][0], z);
                sacc[j] = MFMA_BF16(kf[j][1], qf[t][1], z);
            }
            const bool diagU = (key0 + 63 > qw + 16 * t);  // wave-uniform
            const int qmine = qw + 16 * t + ec;
            #pragma unroll
            for (int j = 0; j < 4; j++) {
                bf16x4 wb;
                #pragma unroll
                for (int v = 0; v < 4; v++) {
                    float tv = sacc[j][v] * C1;
                    float e  = __builtin_amdgcn_exp2f(-fabsf(tv));
                    float w  = fmaxf(tv, 0.f) + __builtin_amdgcn_logf(1.f + e);
                    if (diagU && (key0 + 16 * j + er + v > qmine)) w = 0.f;
                    n2[t] += w * w;
                    wb[v] = (bf16_t)w;
                }
                *(bf16x4*)&wsm[(16 * t + ec) * 72 + 16 * j + er] = wb;  // 4 consecutive keys
            }
        }

        // V fragments (issued here; latency hidden by Ws round-trip waits)
        bf16x8 vf[4][2];
        #pragma unroll
        for (int jd = 0; jd < 4; jd++)
            #pragma unroll
            for (int s2 = 0; s2 < 2; s2++)
                vf[jd][s2] = *(const bf16x8*)&Vb[(16 * jd + lrow) * Tq + key0 + s2 * 32 + lg * 8];

        // O += W V (Ws same-wave in-order DS; no barrier)
        #pragma unroll
        for (int t = 0; t < 2; t++)
            #pragma unroll
            for (int s2 = 0; s2 < 2; s2++) {
                bf16x8 wf = *(const bf16x8*)&wsm[(16 * t + lrow) * 72 + s2 * 32 + lg * 8];
                #pragma unroll
                for (int jd = 0; jd < 4; jd++)
                    oacc[t][jd] = MFMA_BF16(wf, vf[jd][s2], oacc[t][jd]);
            }
    }

    // n2 per lane covers q=qw+16t+ec, keys of its lg group; reduce across lg
    #pragma unroll
    for (int t = 0; t < 2; t++) {
        n2[t] += __shfl_xor(n2[t], 16, 64);
        n2[t] += __shfl_xor(n2[t], 32, 64);
    }

    // partial epilogue (unconditional: empty-range waves must write zeros)
    const int qiL   = Qi * 2 + (wave >> 1);      // 64-row tile index for combine layout
    const int rbase = 32 * (wave & 1);
    bf16_t* Op = (half ? Opart1 : Opart0) + ((size_t)bh * 32 + qiL) * 4096;
    #pragma unroll
    for (int t = 0; t < 2; t++)
        #pragma unroll
        for (int jd = 0; jd < 4; jd++)
            #pragma unroll
            for (int v = 0; v < 4; v++)
                Op[(rbase + 16 * t + er + v) * 64 + 16 * jd + ec] = (bf16_t)oacc[t][jd][v];
    if (lg == 0) {
        #pragma unroll
        for (int t = 0; t < 2; t++)
            n2part[((size_t)(half * 1024 + bh * 32 + qiL)) * 64 + rbase + 16 * t + ec] = n2[t];
    }
}

// ---------- combine partials: ao = (O0+O1) * rsqrt(n20+n21) ----------
__global__ __launch_bounds__(256)
void combine_kernel(const bf16_t* __restrict__ O0, const bf16_t* __restrict__ O1,
                    const float* __restrict__ n2part, bf16_t* __restrict__ ao) {
    const int qi = blockIdx.x;
    const int bh = blockIdx.y;
    const int b = bh >> 4, h = bh & 15;
    const int t = threadIdx.x;
    const size_t base = (size_t)(bh * 32 + qi) * 4096;
    const float* np0 = n2part + (size_t)(bh * 32 + qi) * 64;
    const float* np1 = np0 + (size_t)1024 * 64;
    #pragma unroll
    for (int i = 0; i < 2; i++) {
        int idx = i * 2048 + t * 8;
        int row = idx >> 6, col = idx & 63;
        bf16x8 a = *(const bf16x8*)(O0 + base + idx);
        bf16x8 c = *(const bf16x8*)(O1 + base + idx);
        float inv = rsqrtf(np0[row] + np1[row]);
        bf16x8 o;
        #pragma unroll
        for (int j = 0; j < 8; j++) o[j] = (bf16_t)(((float)a[j] + (float)c[j]) * inv);
        *(bf16x8*)(ao + (size_t)(b * Tq + qi * 64 + row) * Cq + h * HSq + col) = o;
    }
}

// ---------- launch ----------
extern "C" void kernel_launch(void* const* d_in, const int* in_sizes, int n_in,
                              void* d_out, int out_size, void* d_ws, size_t ws_size,
                              hipStream_t stream) {
    const float* x     = (const float*)d_in[0];
    const float* wqkv  = (const float*)d_in[1];
    const float* wproj = (const float*)d_in[2];
    const float* bproj = (const float*)d_in[3];
    float* out = (float*)d_out;

    // workspace layout (56 MB peak)
    char* ws = (char*)d_ws;
    bf16_t* wprojb = (bf16_t*)(ws);                    //  2 MB [0,2)
    bf16_t* xb     = (bf16_t*)(ws + ( 2u << 20));      //  8 MB [2,10)   dead after gemm1
    bf16_t* wqkvb  = (bf16_t*)(ws + (10u << 20));      //  6 MB [10,16)  dead after gemm1
    bf16_t* qcb    = (bf16_t*)(ws + (16u << 20));      //  8 MB [16,24)  Q compact
    bf16_t* kcb    = (bf16_t*)(ws + (24u << 20));      //  8 MB [24,32)  K compact [bh][t][d]
    bf16_t* vtb    = (bf16_t*)(ws + (32u << 20));      //  8 MB [32,40)  V^T [bh][d][t]
    bf16_t* aob    = (bf16_t*)(ws + (40u << 20));      //  8 MB [40,48)
    bf16_t* opart0 = (bf16_t*)(ws + ( 2u << 20));      //  8 MB over dead xb
    float*  n2part = (float*)(ws + (10u << 20));       // 512 KB over dead wqkvb
    bf16_t* opart1 = (bf16_t*)(ws + (48u << 20));      //  8 MB [48,56)

    cvt_f32_bf16<<<1024, 256, 0, stream>>>(wproj, wprojb, Cq * Cq);
    cvt_f32_bf16<<<4096, 256, 0, stream>>>(x, xb, Mrows * Cq);
    cvt_f32_bf16<<<3072, 256, 0, stream>>>(wqkv, wqkvb, 3 * Cq * Cq);

    // QKV projection with fused layout epilogue: Qc / Kc / V^T
    gemm_bt<128, 2><<<dim3(24, 32), 256, 0, stream>>>(xb, wqkvb, nullptr, nullptr,
                                                      qcb, kcb, vtb, Mrows, 3 * Cq, Cq);
    // attention (barrier-free, k-split halves) + combine
    attn_kernel<<<dim3(32, 32), 256, 0, stream>>>(qcb, kcb, vtb, opart0, opart1, n2part);
    combine_kernel<<<dim3(32, 32), 256, 0, stream>>>(opart0, opart1, n2part, aob);
    // output projection + bias
    gemm_bt<64, 1><<<dim3(8, 64), 256, 0, stream>>>(aob, wprojb, (void*)out, bproj,
                                                    nullptr, nullptr, nullptr, Mrows, Cq, Cq);
}